// Round 3
// baseline (100.939 us; speedup 1.0000x reference)
//
#include <hip/hip_runtime.h>

// WaveletSparsityPrior: 3-level Haar pyramid sparsity loss on (64,1,1024,1024) f32.
// One thread owns two 8x8 tiles -> full 3-level pyramid in registers, all *0.5
// scale factors folded into thresholds (coeff* = 2^level x true coeff).
// Stage 1: 2048 blocks x 256 threads (single residency round, 8 blocks/CU),
//          per-block partial sums -> d_ws.
// Stage 2: single block deterministic reduction -> d_out[0].

#define NBLK 2048

typedef float floatx4 __attribute__((ext_vector_type(4)));

// BASE = 50/255. Unscaled-coefficient thresholds: thr_j' = 2^j * thr_j
//   level1: thr = BASE/4 -> thr1' = BASE/2
//   level2: thr = BASE/2 -> thr2' = 2*BASE
//   level3: thr = BASE   -> thr3' = 8*BASE
#define BASE_THR (50.0f / 255.0f)
#define T1P (BASE_THR * 0.5f)
#define T2P (BASE_THR * 2.0f)
#define T3P (BASE_THR * 8.0f)
// weight/(3*N_band) / 2^level:
//   A1' = 1/(9*16777216*2)  = 1/301989888
//   A2' = 1/(6*4194304*4)   = 1/100663296
//   A3' = 1/(3*1048576*8)   = 1/25165824
#define A1P (1.0f / 301989888.0f)
#define A2P (1.0f / 100663296.0f)
#define A3P (1.0f / 25165824.0f)

static __device__ __forceinline__ float band3(float lh, float hl, float hh, float thr) {
    return fminf(fabsf(lh), thr) + fminf(fabsf(hl), thr) + fminf(fabsf(hh), thr);
}

static __device__ __forceinline__ float tile_loss(const float* __restrict__ base) {
    float ll1[4][4];
    float s1 = 0.0f, s2 = 0.0f, s3 = 0.0f;

    // ---- level 1: 8x8 -> 4x4 per band (unscaled) ----
    #pragma unroll
    for (int r = 0; r < 4; ++r) {
        const float* r0 = base + ((size_t)(2 * r) << 10);
        floatx4 a0 = __builtin_nontemporal_load(reinterpret_cast<const floatx4*>(r0));
        floatx4 a1 = __builtin_nontemporal_load(reinterpret_cast<const floatx4*>(r0 + 4));
        floatx4 b0 = __builtin_nontemporal_load(reinterpret_cast<const floatx4*>(r0 + 1024));
        floatx4 b1 = __builtin_nontemporal_load(reinterpret_cast<const floatx4*>(r0 + 1028));
        float lo[8], hi[8];
        #pragma unroll
        for (int k = 0; k < 4; ++k) {
            lo[k]     = a0[k] + b0[k]; hi[k]     = b0[k] - a0[k];
            lo[k + 4] = a1[k] + b1[k]; hi[k + 4] = b1[k] - a1[k];
        }
        #pragma unroll
        for (int c = 0; c < 4; ++c) {
            ll1[r][c] = lo[2 * c] + lo[2 * c + 1];
            float lh = lo[2 * c + 1] - lo[2 * c];
            float hl = hi[2 * c] + hi[2 * c + 1];
            float hh = hi[2 * c + 1] - hi[2 * c];
            s1 += band3(lh, hl, hh, T1P);
        }
    }

    // ---- level 2: 4x4 -> 2x2 per band (unscaled) ----
    float ll2[2][2];
    #pragma unroll
    for (int r = 0; r < 2; ++r) {
        float lo[4], hi[4];
        #pragma unroll
        for (int c = 0; c < 4; ++c) {
            lo[c] = ll1[2 * r][c] + ll1[2 * r + 1][c];
            hi[c] = ll1[2 * r + 1][c] - ll1[2 * r][c];
        }
        #pragma unroll
        for (int c = 0; c < 2; ++c) {
            ll2[r][c] = lo[2 * c] + lo[2 * c + 1];
            float lh = lo[2 * c + 1] - lo[2 * c];
            float hl = hi[2 * c] + hi[2 * c + 1];
            float hh = hi[2 * c + 1] - hi[2 * c];
            s2 += band3(lh, hl, hh, T2P);
        }
    }

    // ---- level 3: 2x2 -> 1x1 per band (unscaled) ----
    {
        float lo0 = ll2[0][0] + ll2[1][0];
        float lo1 = ll2[0][1] + ll2[1][1];
        float hi0 = ll2[1][0] - ll2[0][0];
        float hi1 = ll2[1][1] - ll2[0][1];
        float lh = lo1 - lo0;
        float hl = hi0 + hi1;
        float hh = hi1 - hi0;
        s3 = band3(lh, hl, hh, T3P);
    }

    return s1 * A1P + s2 * A2P + s3 * A3P;
}

__global__ __launch_bounds__(256) void wsp_partial(const float* __restrict__ pred,
                                                   float* __restrict__ partial) {
    const int tid = blockIdx.x * 256 + threadIdx.x;   // 0..524287, one 8x16 strip each
    const int tx = tid & 63;           // 16-wide strip col
    const int ty = (tid >> 6) & 127;   // 8-tall strip row
    const int b  = tid >> 13;          // batch

    const float* base = pred + ((size_t)b << 20) + ((size_t)ty << 13) + ((size_t)tx << 4);

    float c = tile_loss(base) + tile_loss(base + 8);

    __shared__ float red[256];
    red[threadIdx.x] = c;
    __syncthreads();
    #pragma unroll
    for (int off = 128; off > 0; off >>= 1) {
        if (threadIdx.x < off) red[threadIdx.x] += red[threadIdx.x + off];
        __syncthreads();
    }
    if (threadIdx.x == 0) partial[blockIdx.x] = red[0];
}

__global__ __launch_bounds__(256) void wsp_reduce(const float* __restrict__ partial,
                                                  float* __restrict__ out) {
    __shared__ float red[256];
    float s = 0.0f;
    for (int i = threadIdx.x; i < NBLK; i += 256) s += partial[i];
    red[threadIdx.x] = s;
    __syncthreads();
    #pragma unroll
    for (int off = 128; off > 0; off >>= 1) {
        if (threadIdx.x < off) red[threadIdx.x] += red[threadIdx.x + off];
        __syncthreads();
    }
    if (threadIdx.x == 0) out[0] = red[0];
}

extern "C" void kernel_launch(void* const* d_in, const int* in_sizes, int n_in,
                              void* d_out, int out_size, void* d_ws, size_t ws_size,
                              hipStream_t stream) {
    const float* pred = (const float*)d_in[0];
    float* partial = (float*)d_ws;           // needs NBLK*4 = 8 KB
    float* out = (float*)d_out;

    wsp_partial<<<NBLK, 256, 0, stream>>>(pred, partial);
    wsp_reduce<<<1, 256, 0, stream>>>(partial, out);
}

// Round 4
// 74.545 us; speedup vs baseline: 1.3541x; 1.3541x over previous
//
#include <hip/hip_runtime.h>

// WaveletSparsityPrior: 3-level Haar pyramid sparsity loss on (64,1,1024,1024) f32.
// One thread owns one 8x8 tile -> full 3-level pyramid in registers (R1-proven
// access pattern: 32B lane stride, float4 loads, NO nontemporal).
// All *0.5 scale factors folded into thresholds (coeff* = 2^level x true).
// Single kernel: per-block LDS reduce -> one device-scope atomicAdd to d_out[0].
// d_out[0] zeroed each call via hipMemsetAsync (graph-capturable).

#define NBLK 4096

typedef float floatx4 __attribute__((ext_vector_type(4)));

// BASE = 50/255. Unscaled-coefficient thresholds: thr_j' = 2^j * thr_j
#define BASE_THR (50.0f / 255.0f)
#define T1P (BASE_THR * 0.5f)
#define T2P (BASE_THR * 2.0f)
#define T3P (BASE_THR * 8.0f)
// weight/(3*N_band) / 2^level
#define A1P (1.0f / 301989888.0f)
#define A2P (1.0f / 100663296.0f)
#define A3P (1.0f / 25165824.0f)

static __device__ __forceinline__ float band3(float lh, float hl, float hh, float thr) {
    return fminf(fabsf(lh), thr) + fminf(fabsf(hl), thr) + fminf(fabsf(hh), thr);
}

__global__ __launch_bounds__(256) void wsp_loss(const float* __restrict__ pred,
                                                float* __restrict__ out) {
    const int tid = blockIdx.x * 256 + threadIdx.x;   // tile index, 0..1048575
    const int tx = tid & 127;          // tile col
    const int ty = (tid >> 7) & 127;   // tile row
    const int b  = tid >> 14;          // batch

    const float* base = pred + ((size_t)b << 20) + ((size_t)ty << 13) + ((size_t)tx << 3);

    float ll1[4][4];
    float s1 = 0.0f, s2 = 0.0f, s3 = 0.0f;

    // ---- level 1: 8x8 -> 4x4 per band (unscaled) ----
    #pragma unroll
    for (int r = 0; r < 4; ++r) {
        const float* r0 = base + ((size_t)(2 * r) << 10);
        floatx4 a0 = *reinterpret_cast<const floatx4*>(r0);
        floatx4 a1 = *reinterpret_cast<const floatx4*>(r0 + 4);
        floatx4 b0 = *reinterpret_cast<const floatx4*>(r0 + 1024);
        floatx4 b1 = *reinterpret_cast<const floatx4*>(r0 + 1028);
        float lo[8], hi[8];
        #pragma unroll
        for (int k = 0; k < 4; ++k) {
            lo[k]     = a0[k] + b0[k]; hi[k]     = b0[k] - a0[k];
            lo[k + 4] = a1[k] + b1[k]; hi[k + 4] = b1[k] - a1[k];
        }
        #pragma unroll
        for (int c = 0; c < 4; ++c) {
            ll1[r][c] = lo[2 * c] + lo[2 * c + 1];
            float lh = lo[2 * c + 1] - lo[2 * c];
            float hl = hi[2 * c] + hi[2 * c + 1];
            float hh = hi[2 * c + 1] - hi[2 * c];
            s1 += band3(lh, hl, hh, T1P);
        }
    }

    // ---- level 2: 4x4 -> 2x2 per band (unscaled) ----
    float ll2[2][2];
    #pragma unroll
    for (int r = 0; r < 2; ++r) {
        float lo[4], hi[4];
        #pragma unroll
        for (int c = 0; c < 4; ++c) {
            lo[c] = ll1[2 * r][c] + ll1[2 * r + 1][c];
            hi[c] = ll1[2 * r + 1][c] - ll1[2 * r][c];
        }
        #pragma unroll
        for (int c = 0; c < 2; ++c) {
            ll2[r][c] = lo[2 * c] + lo[2 * c + 1];
            float lh = lo[2 * c + 1] - lo[2 * c];
            float hl = hi[2 * c] + hi[2 * c + 1];
            float hh = hi[2 * c + 1] - hi[2 * c];
            s2 += band3(lh, hl, hh, T2P);
        }
    }

    // ---- level 3: 2x2 -> 1x1 per band (unscaled) ----
    {
        float lo0 = ll2[0][0] + ll2[1][0];
        float lo1 = ll2[0][1] + ll2[1][1];
        float hi0 = ll2[1][0] - ll2[0][0];
        float hi1 = ll2[1][1] - ll2[0][1];
        float lh = lo1 - lo0;
        float hl = hi0 + hi1;
        float hh = hi1 - hi0;
        s3 = band3(lh, hl, hh, T3P);
    }

    float c = s1 * A1P + s2 * A2P + s3 * A3P;

    __shared__ float red[256];
    red[threadIdx.x] = c;
    __syncthreads();
    #pragma unroll
    for (int off = 128; off > 0; off >>= 1) {
        if (threadIdx.x < off) red[threadIdx.x] += red[threadIdx.x + off];
        __syncthreads();
    }
    if (threadIdx.x == 0) atomicAdd(out, red[0]);
}

extern "C" void kernel_launch(void* const* d_in, const int* in_sizes, int n_in,
                              void* d_out, int out_size, void* d_ws, size_t ws_size,
                              hipStream_t stream) {
    const float* pred = (const float*)d_in[0];
    float* out = (float*)d_out;

    hipMemsetAsync(out, 0, sizeof(float), stream);
    wsp_loss<<<NBLK, 256, 0, stream>>>(pred, out);
}

// Round 5
// 46.726 us; speedup vs baseline: 2.1602x; 1.5953x over previous
//
#include <hip/hip_runtime.h>

// WaveletSparsityPrior: 3-level Haar pyramid sparsity loss on (64,1,1024,1024) f32.
// One thread owns one 8x8 tile -> full 3-level pyramid in registers; each thread
// processes TWO tiles via grid-stride (tid and tid+524288) -> 2048 blocks =
// exactly one residency round (8 blocks/CU x 256 CU), 32 independent loads in
// flight per thread. Access pattern per tile identical to the proven R1 kernel
// (32B lane stride, float4 pairs covering contiguous 2KB per wave, no nt).
// All *0.5 scale factors folded into thresholds (coeff* = 2^level x true).
// Stage 2: single-block deterministic reduction of 2048 partials -> d_out[0].

#define NBLK 2048
#define TILE_STRIDE (NBLK * 256)   // 524288

typedef float floatx4 __attribute__((ext_vector_type(4)));

// BASE = 50/255. Unscaled-coefficient thresholds: thr_j' = 2^j * thr_j
#define BASE_THR (50.0f / 255.0f)
#define T1P (BASE_THR * 0.5f)
#define T2P (BASE_THR * 2.0f)
#define T3P (BASE_THR * 8.0f)
// weight/(3*N_band) / 2^level
#define A1P (1.0f / 301989888.0f)
#define A2P (1.0f / 100663296.0f)
#define A3P (1.0f / 25165824.0f)

static __device__ __forceinline__ float band3(float lh, float hl, float hh, float thr) {
    return fminf(fabsf(lh), thr) + fminf(fabsf(hl), thr) + fminf(fabsf(hh), thr);
}

static __device__ __forceinline__ float tile_loss(const float* __restrict__ pred, int tile) {
    const int tx = tile & 127;          // tile col
    const int ty = (tile >> 7) & 127;   // tile row
    const int b  = tile >> 14;          // batch
    const float* base = pred + ((size_t)b << 20) + ((size_t)ty << 13) + ((size_t)tx << 3);

    float ll1[4][4];
    float s1 = 0.0f, s2 = 0.0f, s3 = 0.0f;

    // ---- level 1: 8x8 -> 4x4 per band (unscaled) ----
    #pragma unroll
    for (int r = 0; r < 4; ++r) {
        const float* r0 = base + ((size_t)(2 * r) << 10);
        floatx4 a0 = *reinterpret_cast<const floatx4*>(r0);
        floatx4 a1 = *reinterpret_cast<const floatx4*>(r0 + 4);
        floatx4 b0 = *reinterpret_cast<const floatx4*>(r0 + 1024);
        floatx4 b1 = *reinterpret_cast<const floatx4*>(r0 + 1028);
        float lo[8], hi[8];
        #pragma unroll
        for (int k = 0; k < 4; ++k) {
            lo[k]     = a0[k] + b0[k]; hi[k]     = b0[k] - a0[k];
            lo[k + 4] = a1[k] + b1[k]; hi[k + 4] = b1[k] - a1[k];
        }
        #pragma unroll
        for (int c = 0; c < 4; ++c) {
            ll1[r][c] = lo[2 * c] + lo[2 * c + 1];
            float lh = lo[2 * c + 1] - lo[2 * c];
            float hl = hi[2 * c] + hi[2 * c + 1];
            float hh = hi[2 * c + 1] - hi[2 * c];
            s1 += band3(lh, hl, hh, T1P);
        }
    }

    // ---- level 2: 4x4 -> 2x2 per band (unscaled) ----
    float ll2[2][2];
    #pragma unroll
    for (int r = 0; r < 2; ++r) {
        float lo[4], hi[4];
        #pragma unroll
        for (int c = 0; c < 4; ++c) {
            lo[c] = ll1[2 * r][c] + ll1[2 * r + 1][c];
            hi[c] = ll1[2 * r + 1][c] - ll1[2 * r][c];
        }
        #pragma unroll
        for (int c = 0; c < 2; ++c) {
            ll2[r][c] = lo[2 * c] + lo[2 * c + 1];
            float lh = lo[2 * c + 1] - lo[2 * c];
            float hl = hi[2 * c] + hi[2 * c + 1];
            float hh = hi[2 * c + 1] - hi[2 * c];
            s2 += band3(lh, hl, hh, T2P);
        }
    }

    // ---- level 3: 2x2 -> 1x1 per band (unscaled) ----
    float lo0 = ll2[0][0] + ll2[1][0];
    float lo1 = ll2[0][1] + ll2[1][1];
    float hi0 = ll2[1][0] - ll2[0][0];
    float hi1 = ll2[1][1] - ll2[0][1];
    s3 = band3(lo1 - lo0, hi0 + hi1, hi1 - hi0, T3P);

    return s1 * A1P + s2 * A2P + s3 * A3P;
}

__global__ __launch_bounds__(256) void wsp_partial(const float* __restrict__ pred,
                                                   float* __restrict__ partial) {
    const int tid = blockIdx.x * 256 + threadIdx.x;   // 0..524287

    float c = tile_loss(pred, tid) + tile_loss(pred, tid + TILE_STRIDE);

    __shared__ float red[256];
    red[threadIdx.x] = c;
    __syncthreads();
    #pragma unroll
    for (int off = 128; off > 0; off >>= 1) {
        if (threadIdx.x < off) red[threadIdx.x] += red[threadIdx.x + off];
        __syncthreads();
    }
    if (threadIdx.x == 0) partial[blockIdx.x] = red[0];
}

__global__ __launch_bounds__(256) void wsp_reduce(const float* __restrict__ partial,
                                                  float* __restrict__ out) {
    __shared__ float red[256];
    float s = 0.0f;
    for (int i = threadIdx.x; i < NBLK; i += 256) s += partial[i];
    red[threadIdx.x] = s;
    __syncthreads();
    #pragma unroll
    for (int off = 128; off > 0; off >>= 1) {
        if (threadIdx.x < off) red[threadIdx.x] += red[threadIdx.x + off];
        __syncthreads();
    }
    if (threadIdx.x == 0) out[0] = red[0];
}

extern "C" void kernel_launch(void* const* d_in, const int* in_sizes, int n_in,
                              void* d_out, int out_size, void* d_ws, size_t ws_size,
                              hipStream_t stream) {
    const float* pred = (const float*)d_in[0];
    float* partial = (float*)d_ws;           // needs NBLK*4 = 8 KB
    float* out = (float*)d_out;

    wsp_partial<<<NBLK, 256, 0, stream>>>(pred, partial);
    wsp_reduce<<<1, 256, 0, stream>>>(partial, out);
}